// Round 2
// baseline (210.053 us; speedup 1.0000x reference)
//
#include <hip/hip_runtime.h>
#include <stdint.h>

#define B_SZ 2
#define T_SEQ 2048
#define D_MODEL 1024
#define NHEADS 16
#define HDIM 64
#define QKV_P (3 * D_MODEL) /* 3072 */

typedef unsigned short u16;
typedef __attribute__((ext_vector_type(4))) float f32x4;
typedef __attribute__((ext_vector_type(8))) short s16x8;

__device__ __forceinline__ u16 f2bf(float f) {
  union { float f; uint32_t u; } v; v.f = f;
  uint32_t r = v.u + 0x7fffu + ((v.u >> 16) & 1u);
  return (u16)(r >> 16);
}

__device__ __forceinline__ void async16(const void* g, void* l) {
  __builtin_amdgcn_global_load_lds((const __attribute__((address_space(1))) void*)g,
                                   (__attribute__((address_space(3))) void*)l,
                                   16, 0, 0);
}

// ---------------- fp32 -> bf16 convert (x) ----------------
__global__ void convert_bf16_kernel(const float* __restrict__ in, u16* __restrict__ out, int n4) {
  int i = blockIdx.x * blockDim.x + threadIdx.x;
  if (i < n4) {
    float4 v = ((const float4*)in)[i];
    ushort4 o;
    o.x = f2bf(v.x); o.y = f2bf(v.y); o.z = f2bf(v.z); o.w = f2bf(v.w);
    ((ushort4*)out)[i] = o;
  }
}

// ---------------- fp32 [R][C] -> bf16 [C][R] (weights) ----------------
__global__ void transpose_convert(const float* __restrict__ in, u16* __restrict__ out, int R, int C) {
  __shared__ float tile[32][33];
  const int tx = threadIdx.x, ty = threadIdx.y;
  const int c0 = blockIdx.x * 32, r0 = blockIdx.y * 32;
#pragma unroll
  for (int i = 0; i < 4; i++)
    tile[ty + i * 8][tx] = in[(size_t)(r0 + ty + i * 8) * C + c0 + tx];
  __syncthreads();
#pragma unroll
  for (int i = 0; i < 4; i++)
    out[(size_t)(c0 + ty + i * 8) * R + r0 + tx] = f2bf(tile[tx][ty + i * 8]);
}

// ---------------- V section of qkv -> VT[bh*64+hd][T] ----------------
__global__ void transpose_v(const u16* __restrict__ qkv, u16* __restrict__ vT) {
  __shared__ u16 tile[32][33];
  const int tx = threadIdx.x, ty = threadIdx.y;
  const int tt = blockIdx.x * 32;
  const int bh = blockIdx.y >> 1, hdt = blockIdx.y & 1;
  const int b = bh >> 4, h = bh & 15;
  const int hh = hdt * 32;
#pragma unroll
  for (int i = 0; i < 4; i++)
    tile[ty + i * 8][tx] =
        qkv[(size_t)(b * T_SEQ + tt + ty + i * 8) * QKV_P + 2 * D_MODEL + h * HDIM + hh + tx];
  __syncthreads();
#pragma unroll
  for (int i = 0; i < 4; i++)
    vT[(size_t)(bh * HDIM + hh + ty + i * 8) * T_SEQ + tt + tx] = tile[tx][ty + i * 8];
}

// ---------------- m97-style bf16 GEMM: C[M,N] = A[M,K] * BT[N,K]^T ----------------
template <int F32OUT>
__global__ __launch_bounds__(256) void gemm_bt(const u16* __restrict__ A,
                                               const u16* __restrict__ BT,
                                               void* __restrict__ Cout,
                                               int M, int N, int K) {
  __shared__ u16 As[128 * 32];
  __shared__ u16 Bs[128 * 32];
  const int tid = threadIdx.x;
  const int lane = tid & 63, w = tid >> 6;
  const int l15 = lane & 15, g = lane >> 4;
  const int wr = w >> 1, wc = w & 1;
  const int bn = blockIdx.x, bm = blockIdx.y;
  const u16* Ab = A + (size_t)bm * 128 * K;
  const u16* Bb = BT + (size_t)bn * 128 * K;
  f32x4 acc[4][4];
#pragma unroll
  for (int i = 0; i < 4; i++)
#pragma unroll
    for (int j = 0; j < 4; j++) acc[i][j] = (f32x4){0.f, 0.f, 0.f, 0.f};
  const int c0 = tid, c1 = tid + 256;
  for (int kt = 0; kt < K; kt += 32) {
    async16(Ab + (size_t)(c0 >> 2) * K + kt + (c0 & 3) * 8, (char*)As + c0 * 16);
    async16(Ab + (size_t)(c1 >> 2) * K + kt + (c1 & 3) * 8, (char*)As + c1 * 16);
    async16(Bb + (size_t)(c0 >> 2) * K + kt + (c0 & 3) * 8, (char*)Bs + c0 * 16);
    async16(Bb + (size_t)(c1 >> 2) * K + kt + (c1 & 3) * 8, (char*)Bs + c1 * 16);
    asm volatile("s_waitcnt vmcnt(0)" ::: "memory");
    __syncthreads();
    s16x8 af[4], bfr[4];
#pragma unroll
    for (int i = 0; i < 4; i++)
      af[i] = *(const s16x8*)(As + (wr * 64 + i * 16 + l15) * 32 + g * 8);
#pragma unroll
    for (int j = 0; j < 4; j++)
      bfr[j] = *(const s16x8*)(Bs + (wc * 64 + j * 16 + l15) * 32 + g * 8);
#pragma unroll
    for (int i = 0; i < 4; i++)
#pragma unroll
      for (int j = 0; j < 4; j++)
        acc[i][j] = __builtin_amdgcn_mfma_f32_16x16x32_bf16(af[i], bfr[j], acc[i][j], 0, 0, 0);
    __syncthreads();
  }
#pragma unroll
  for (int i = 0; i < 4; i++) {
    const int row0 = bm * 128 + wr * 64 + i * 16 + g * 4;
#pragma unroll
    for (int j = 0; j < 4; j++) {
      const int col = bn * 128 + wc * 64 + j * 16 + l15;
#pragma unroll
      for (int r = 0; r < 4; r++) {
        if (F32OUT)
          ((float*)Cout)[(size_t)(row0 + r) * N + col] = acc[i][j][r];
        else
          ((u16*)Cout)[(size_t)(row0 + r) * N + col] = f2bf(acc[i][j][r]);
      }
    }
  }
}

// ---------------- causal flash attention ----------------
// grid (T/64, B*NH); 256 threads; wave w handles q-rows [qt*64 + w*16, +16)
__global__ __launch_bounds__(256) void flash_attn(const u16* __restrict__ qkv,
                                                  const u16* __restrict__ vT,
                                                  u16* __restrict__ attn) {
  __shared__ u16 Ks[64 * 64];        // [key][hd], XOR-swizzled
  __shared__ u16 Vs[64 * 64];        // [hd][key], XOR-swizzled
  __shared__ u16 Ps[4][16 * 72];     // per-wave P tile, padded pitch 72
  const int tid = threadIdx.x;
  const int lane = tid & 63, w = tid >> 6;
  const int l15 = lane & 15, g = lane >> 4;
  const int qt = blockIdx.x, bh = blockIdx.y;
  const int b = bh >> 4, h = bh & 15;

  // Q fragments (A-layout: row = lane&15, k = (lane>>4)*8+j), kept in regs
  const size_t qrow = (size_t)(b * T_SEQ + qt * 64 + w * 16 + l15);
  s16x8 qf[2];
  qf[0] = *(const s16x8*)(qkv + qrow * QKV_P + h * HDIM + 0 * 32 + g * 8);
  qf[1] = *(const s16x8*)(qkv + qrow * QKV_P + h * HDIM + 1 * 32 + g * 8);

  f32x4 O[4];
#pragma unroll
  for (int t = 0; t < 4; t++) O[t] = (f32x4){0.f, 0.f, 0.f, 0.f};
  float m_r[4] = {-1e30f, -1e30f, -1e30f, -1e30f};
  float l_r[4] = {0.f, 0.f, 0.f, 0.f};
  const float sc = 0.18033688011112042f; // (1/sqrt(64)) * log2(e)

  for (int kvt = 0; kvt <= qt; ++kvt) {
    // stage K and VT tiles: 512 16B chunks each; linear LDS dest, inverse-swizzled source
#pragma unroll
    for (int i = 0; i < 2; i++) {
      int o = (tid + i * 256) * 16;
      int lo = o ^ (((o >> 7) & 7) << 4);
      int row = lo >> 7;     // key (K) / hd (V)
      int byt = lo & 127;
      async16(qkv + (size_t)(b * T_SEQ + kvt * 64 + row) * QKV_P + D_MODEL + h * HDIM + (byt >> 1),
              (char*)Ks + o);
      async16(vT + (size_t)(bh * HDIM + row) * T_SEQ + kvt * 64 + (byt >> 1),
              (char*)Vs + o);
    }
    asm volatile("s_waitcnt vmcnt(0)" ::: "memory");
    __syncthreads();

    // S = Q K^T
    f32x4 S[4];
#pragma unroll
    for (int t = 0; t < 4; t++) S[t] = (f32x4){0.f, 0.f, 0.f, 0.f};
#pragma unroll
    for (int t16 = 0; t16 < 4; t16++) {
#pragma unroll
      for (int kk = 0; kk < 2; kk++) {
        int key = t16 * 16 + l15;
        int bl = key * 128 + kk * 64 + g * 16;
        int bp = bl ^ ((key & 7) << 4);
        s16x8 kf = *(const s16x8*)((const char*)Ks + bp);
        S[t16] = __builtin_amdgcn_mfma_f32_16x16x32_bf16(qf[kk], kf, S[t16], 0, 0, 0);
      }
    }

    const bool diag = (kvt == qt);
#pragma unroll
    for (int r = 0; r < 4; r++) {
      const int rowq = w * 16 + g * 4 + r;
      float x[4];
#pragma unroll
      for (int t16 = 0; t16 < 4; t16++) {
        float s = S[t16][r] * sc;
        if (diag && (t16 * 16 + l15) > rowq) s = -3e38f;
        x[t16] = s;
      }
      float mx = fmaxf(fmaxf(x[0], x[1]), fmaxf(x[2], x[3]));
#pragma unroll
      for (int msk = 1; msk < 16; msk <<= 1) mx = fmaxf(mx, __shfl_xor(mx, msk));
      const float mnew = fmaxf(m_r[r], mx);
      const float alpha = exp2f(m_r[r] - mnew);
      m_r[r] = mnew;
      float ps = 0.f;
#pragma unroll
      for (int t16 = 0; t16 < 4; t16++) {
        float p = exp2f(x[t16] - mnew);
        ps += p;
        Ps[w][(g * 4 + r) * 72 + t16 * 16 + l15] = f2bf(p);
      }
#pragma unroll
      for (int msk = 1; msk < 16; msk <<= 1) ps += __shfl_xor(ps, msk);
      l_r[r] = l_r[r] * alpha + ps;
#pragma unroll
      for (int t = 0; t < 4; t++) O[t][r] *= alpha;
    }

    // ensure P writes visible to the wave's reads (wave-private buffer, order only)
    asm volatile("s_waitcnt lgkmcnt(0)" ::: "memory");

    // O += P V
#pragma unroll
    for (int kk = 0; kk < 2; kk++) {
      s16x8 pf = *(const s16x8*)(&Ps[w][l15 * 72 + kk * 32 + g * 8]);
#pragma unroll
      for (int t = 0; t < 4; t++) {
        int hd = t * 16 + l15;
        int bl = hd * 128 + kk * 64 + g * 16;
        int bp = bl ^ ((hd & 7) << 4);
        s16x8 vf = *(const s16x8*)((const char*)Vs + bp);
        O[t] = __builtin_amdgcn_mfma_f32_16x16x32_bf16(pf, vf, O[t], 0, 0, 0);
      }
    }
    __syncthreads();
  }

#pragma unroll
  for (int r = 0; r < 4; r++) {
    const float inv = 1.0f / l_r[r];
    const size_t row = (size_t)(b * T_SEQ + qt * 64 + w * 16 + g * 4 + r);
#pragma unroll
    for (int t = 0; t < 4; t++)
      attn[row * D_MODEL + h * HDIM + t * 16 + l15] = f2bf(O[t][r] * inv);
  }
}

extern "C" void kernel_launch(void* const* d_in, const int* in_sizes, int n_in,
                              void* d_out, int out_size, void* d_ws, size_t ws_size,
                              hipStream_t stream) {
  const float* x = (const float*)d_in[0];
  const float* w_qkv = (const float*)d_in[1];
  const float* w_proj = (const float*)d_in[2];
  float* out = (float*)d_out;
  char* ws = (char*)d_ws;
  const size_t MB = (size_t)1 << 20;
  if (ws_size < 56 * MB) return;  // need 56 MB scratch
  u16* xb = (u16*)(ws + 0);            // 8 MB  [4096][1024] bf16
  u16* wqkvT = (u16*)(ws + 8 * MB);    // 6 MB  [3072][1024] bf16
  u16* wprojT = (u16*)(ws + 14 * MB);  // 2 MB  [1024][1024] bf16
  u16* qkv = (u16*)(ws + 16 * MB);     // 24 MB [4096][3072] bf16
  u16* vT = (u16*)(ws + 40 * MB);      // 8 MB  [32*64][2048] bf16
  u16* attn = (u16*)(ws + 48 * MB);    // 8 MB  [4096][1024] bf16

  convert_bf16_kernel<<<4096, 256, 0, stream>>>(x, xb, (B_SZ * T_SEQ * D_MODEL) / 4);
  transpose_convert<<<dim3(96, 32), dim3(32, 8), 0, stream>>>(w_qkv, wqkvT, D_MODEL, QKV_P);
  transpose_convert<<<dim3(32, 32), dim3(32, 8), 0, stream>>>(w_proj, wprojT, D_MODEL, D_MODEL);
  gemm_bt<0><<<dim3(QKV_P / 128, (B_SZ * T_SEQ) / 128), 256, 0, stream>>>(
      xb, wqkvT, qkv, B_SZ * T_SEQ, QKV_P, D_MODEL);
  transpose_v<<<dim3(T_SEQ / 32, B_SZ * NHEADS * 2), dim3(32, 8), 0, stream>>>(qkv, vT);
  flash_attn<<<dim3(T_SEQ / 64, B_SZ * NHEADS), 256, 0, stream>>>(qkv, vT, attn);
  gemm_bt<1><<<dim3(D_MODEL / 128, (B_SZ * T_SEQ) / 128), 256, 0, stream>>>(
      attn, wprojT, out, B_SZ * T_SEQ, D_MODEL, D_MODEL);
}

// Round 4
// 190.796 us; speedup vs baseline: 1.1009x; 1.1009x over previous
//
#include <hip/hip_runtime.h>
#include <stdint.h>

#define B_SZ 2
#define T_SEQ 2048
#define D_MODEL 1024
#define NHEADS 16
#define HDIM 64
#define QKV_P (3 * D_MODEL) /* 3072 */

typedef unsigned short u16;
typedef uint32_t u32;
typedef __attribute__((ext_vector_type(4))) float f32x4;
typedef __attribute__((ext_vector_type(8))) short s16x8;

__device__ __forceinline__ u16 f2bf(float f) {
  union { float f; uint32_t u; } v; v.f = f;
  uint32_t r = v.u + 0x7fffu + ((v.u >> 16) & 1u);
  return (u16)(r >> 16);
}

__device__ __forceinline__ void async16(const void* g, void* l) {
  __builtin_amdgcn_global_load_lds((const __attribute__((address_space(1))) void*)g,
                                   (__attribute__((address_space(3))) void*)l,
                                   16, 0, 0);
}

// ---------------- fp32 -> bf16 convert (x) ----------------
__global__ void convert_bf16_kernel(const float* __restrict__ in, u16* __restrict__ out, int n4) {
  int i = blockIdx.x * blockDim.x + threadIdx.x;
  if (i < n4) {
    float4 v = ((const float4*)in)[i];
    ushort4 o;
    o.x = f2bf(v.x); o.y = f2bf(v.y); o.z = f2bf(v.z); o.w = f2bf(v.w);
    ((ushort4*)out)[i] = o;
  }
}

// ---------------- fp32 [R][C] -> bf16 [C][R] (weights) ----------------
__global__ void transpose_convert(const float* __restrict__ in, u16* __restrict__ out, int R, int C) {
  __shared__ float tile[32][33];
  const int tx = threadIdx.x, ty = threadIdx.y;
  const int c0 = blockIdx.x * 32, r0 = blockIdx.y * 32;
#pragma unroll
  for (int i = 0; i < 4; i++)
    tile[ty + i * 8][tx] = in[(size_t)(r0 + ty + i * 8) * C + c0 + tx];
  __syncthreads();
#pragma unroll
  for (int i = 0; i < 4; i++)
    out[(size_t)(c0 + ty + i * 8) * R + r0 + tx] = f2bf(tile[tx][ty + i * 8]);
}

// ---------------- V section of qkv -> VT[bh*64+hd][T] ----------------
__global__ void transpose_v(const u16* __restrict__ qkv, u16* __restrict__ vT) {
  __shared__ u16 tile[32][33];
  const int tx = threadIdx.x, ty = threadIdx.y;
  const int tt = blockIdx.x * 32;
  const int bh = blockIdx.y >> 1, hdt = blockIdx.y & 1;
  const int b = bh >> 4, h = bh & 15;
  const int hh = hdt * 32;
#pragma unroll
  for (int i = 0; i < 4; i++)
    tile[ty + i * 8][tx] =
        qkv[(size_t)(b * T_SEQ + tt + ty + i * 8) * QKV_P + 2 * D_MODEL + h * HDIM + hh + tx];
  __syncthreads();
#pragma unroll
  for (int i = 0; i < 4; i++)
    vT[(size_t)(bh * HDIM + hh + ty + i * 8) * T_SEQ + tt + tx] = tile[tx][ty + i * 8];
}

// ---------------- m97-style bf16 GEMM: C[M,N] = A[M,K] * BT[N,K]^T ----------------
template <int F32OUT>
__global__ __launch_bounds__(256) void gemm_bt(const u16* __restrict__ A,
                                               const u16* __restrict__ BT,
                                               void* __restrict__ Cout,
                                               int M, int N, int K) {
  __shared__ u16 As[128 * 32];
  __shared__ u16 Bs[128 * 32];
  const int tid = threadIdx.x;
  const int lane = tid & 63, w = tid >> 6;
  const int l15 = lane & 15, g = lane >> 4;
  const int wr = w >> 1, wc = w & 1;
  const int bn = blockIdx.x, bm = blockIdx.y;
  const u16* Ab = A + (size_t)bm * 128 * K;
  const u16* Bb = BT + (size_t)bn * 128 * K;
  f32x4 acc[4][4];
#pragma unroll
  for (int i = 0; i < 4; i++)
#pragma unroll
    for (int j = 0; j < 4; j++) acc[i][j] = (f32x4){0.f, 0.f, 0.f, 0.f};
  const int c0 = tid, c1 = tid + 256;
  for (int kt = 0; kt < K; kt += 32) {
    async16(Ab + (size_t)(c0 >> 2) * K + kt + (c0 & 3) * 8, (char*)As + c0 * 16);
    async16(Ab + (size_t)(c1 >> 2) * K + kt + (c1 & 3) * 8, (char*)As + c1 * 16);
    async16(Bb + (size_t)(c0 >> 2) * K + kt + (c0 & 3) * 8, (char*)Bs + c0 * 16);
    async16(Bb + (size_t)(c1 >> 2) * K + kt + (c1 & 3) * 8, (char*)Bs + c1 * 16);
    asm volatile("s_waitcnt vmcnt(0)" ::: "memory");
    __syncthreads();
    s16x8 af[4], bfr[4];
#pragma unroll
    for (int i = 0; i < 4; i++)
      af[i] = *(const s16x8*)(As + (wr * 64 + i * 16 + l15) * 32 + g * 8);
#pragma unroll
    for (int j = 0; j < 4; j++)
      bfr[j] = *(const s16x8*)(Bs + (wc * 64 + j * 16 + l15) * 32 + g * 8);
#pragma unroll
    for (int i = 0; i < 4; i++)
#pragma unroll
      for (int j = 0; j < 4; j++)
        acc[i][j] = __builtin_amdgcn_mfma_f32_16x16x32_bf16(af[i], bfr[j], acc[i][j], 0, 0, 0);
    __syncthreads();
  }
#pragma unroll
  for (int i = 0; i < 4; i++) {
    const int row0 = bm * 128 + wr * 64 + i * 16 + g * 4;
#pragma unroll
    for (int j = 0; j < 4; j++) {
      const int col = bn * 128 + wc * 64 + j * 16 + l15;
#pragma unroll
      for (int r = 0; r < 4; r++) {
        if (F32OUT)
          ((float*)Cout)[(size_t)(row0 + r) * N + col] = acc[i][j][r];
        else
          ((u16*)Cout)[(size_t)(row0 + r) * N + col] = f2bf(acc[i][j][r]);
      }
    }
  }
}

// ---------------- causal flash attention (swapped-QK^T, double-buffered) ----------------
// grid (T/64, B*NH); 256 threads; wave w owns q-rows [qt*64 + w*16, +16), lane l15 = one q-row
#define PP 88  /* P tile pitch in elements; 176B rows -> 16B-aligned b128, 2-way banks */
__global__ __launch_bounds__(256) void flash_attn(const u16* __restrict__ qkv,
                                                  const u16* __restrict__ vT,
                                                  u16* __restrict__ attn) {
  __shared__ u16 Ks[2][64 * 64];     // [key][hd], XOR-swizzled
  __shared__ u16 Vs[2][64 * 64];     // [hd][key], XOR-swizzled
  __shared__ u16 Ps[4][16 * PP];     // per-wave P^T re-shape buffer
  const int tid = threadIdx.x;
  const int lane = tid & 63, w = tid >> 6;
  const int l15 = lane & 15, g = lane >> 4;
  const int qt = (gridDim.x - 1) - blockIdx.x;  // heavy (large-qt) blocks dispatch first
  const int bh = blockIdx.y;
  const int b = bh >> 4, h = bh & 15;

  // Q fragments (A/B-layout: row = lane&15, k = (lane>>4)*8+j), kept in regs
  const size_t qrow = (size_t)(b * T_SEQ + qt * 64 + w * 16 + l15);
  s16x8 qf[2];
  qf[0] = *(const s16x8*)(qkv + qrow * QKV_P + h * HDIM + 0 * 32 + g * 8);
  qf[1] = *(const s16x8*)(qkv + qrow * QKV_P + h * HDIM + 1 * 32 + g * 8);

  f32x4 O[4];  // O^T fragments: lane holds O[hd = t*16+g*4+r][query = l15]
#pragma unroll
  for (int t = 0; t < 4; t++) O[t] = (f32x4){0.f, 0.f, 0.f, 0.f};
  float m_s = -1e30f, l_s = 0.f;           // per-lane scalars: lane owns one q-row
  const int qrl = w * 16 + l15;            // block-local query row
  const float sc = 0.18033688011112042f;   // (1/sqrt(64)) * log2(e)

  // stage tile kvt into buffer buf: 512 16B chunks each for K and VT;
  // linear LDS dest + inverse-swizzled global source (both-sides swizzle)
#define STAGE(buf, kvt_)                                                                     \
  do {                                                                                       \
    _Pragma("unroll") for (int i_ = 0; i_ < 2; i_++) {                                       \
      int o_ = (tid + i_ * 256) * 16;                                                        \
      int lo_ = o_ ^ (((o_ >> 7) & 7) << 4);                                                 \
      int row_ = lo_ >> 7;                                                                   \
      int byt_ = lo_ & 127;                                                                  \
      async16(qkv + (size_t)(b * T_SEQ + (kvt_) * 64 + row_) * QKV_P + D_MODEL + h * HDIM +  \
                  (byt_ >> 1),                                                               \
              (char*)Ks[buf] + o_);                                                          \
      async16(vT + (size_t)(bh * HDIM + row_) * T_SEQ + (kvt_) * 64 + (byt_ >> 1),           \
              (char*)Vs[buf] + o_);                                                          \
    }                                                                                        \
  } while (0)

  STAGE(0, 0);
  int cur = 0;
  for (int kvt = 0; kvt <= qt; ++kvt) {
    const bool pf = (kvt < qt);
    if (pf) {
      STAGE(cur ^ 1, kvt + 1);
      asm volatile("s_waitcnt vmcnt(4)" ::: "memory");  // current tile's 4 loads done
    } else {
      asm volatile("s_waitcnt vmcnt(0)" ::: "memory");
    }
    __syncthreads();

    // S^T = K Q^T (swapped): D[key16][query]; lane holds S[query=l15][key=t16*16+g*4+r]
    f32x4 S4[4];
#pragma unroll
    for (int t16 = 0; t16 < 4; t16++) S4[t16] = (f32x4){0.f, 0.f, 0.f, 0.f};
#pragma unroll
    for (int t16 = 0; t16 < 4; t16++) {
#pragma unroll
      for (int kk = 0; kk < 2; kk++) {
        int key = t16 * 16 + l15;
        int bl = key * 128 + kk * 64 + g * 16;
        int bp = bl ^ ((key & 7) << 4);
        s16x8 kf = *(const s16x8*)((const char*)Ks[cur] + bp);
        S4[t16] = __builtin_amdgcn_mfma_f32_16x16x32_bf16(kf, qf[kk], S4[t16], 0, 0, 0);
      }
    }

    float x[16];
#pragma unroll
    for (int t16 = 0; t16 < 4; t16++)
#pragma unroll
      for (int r = 0; r < 4; r++) x[t16 * 4 + r] = S4[t16][r] * sc;
    if (kvt == qt) {
#pragma unroll
      for (int t16 = 0; t16 < 4; t16++)
#pragma unroll
        for (int r = 0; r < 4; r++)
          if (t16 * 16 + g * 4 + r > qrl) x[t16 * 4 + r] = -3e38f;
    }
    // row max: 15 in-reg + 2 shfl (across the 4 lanes sharing this query)
    float mx = x[0];
#pragma unroll
    for (int i = 1; i < 16; i++) mx = fmaxf(mx, x[i]);
    mx = fmaxf(mx, __shfl_xor(mx, 16));
    mx = fmaxf(mx, __shfl_xor(mx, 32));
    const float mnew = fmaxf(m_s, mx);
    const float alpha = exp2f(m_s - mnew);
    m_s = mnew;
    float ps = 0.f;
    u16 pb[16];
#pragma unroll
    for (int i = 0; i < 16; i++) {
      float p = exp2f(x[i] - mnew);
      ps += p;
      pb[i] = f2bf(p);
    }
    ps += __shfl_xor(ps, 16);
    ps += __shfl_xor(ps, 32);
    l_s = l_s * alpha + ps;
#pragma unroll
    for (int t = 0; t < 4; t++)
#pragma unroll
      for (int r = 0; r < 4; r++) O[t][r] *= alpha;

    // write P[query=l15][key] pairs to per-wave LDS (key = t16*16+g*4+{0..3})
#pragma unroll
    for (int t16 = 0; t16 < 4; t16++)
#pragma unroll
      for (int pr = 0; pr < 2; pr++) {
        u32 w32 = (u32)pb[t16 * 4 + pr * 2] | ((u32)pb[t16 * 4 + pr * 2 + 1] << 16);
        *(u32*)((char*)&Ps[w][0] + (l15 * PP + t16 * 16 + g * 4 + pr * 2) * 2) = w32;
      }
    asm volatile("s_waitcnt lgkmcnt(0)" ::: "memory");

    // O^T += V^T P^T : mfma(A=V^T-frag, B=P-frag)
#pragma unroll
    for (int kk = 0; kk < 2; kk++) {
      s16x8 pfr = *(const s16x8*)((const char*)&Ps[w][0] + l15 * (PP * 2) + kk * 64 + g * 16);
#pragma unroll
      for (int t = 0; t < 4; t++) {
        int hd = t * 16 + l15;
        int bl = hd * 128 + kk * 64 + g * 16;
        int bp = bl ^ ((hd & 7) << 4);
        s16x8 vf = *(const s16x8*)((const char*)Vs[cur] + bp);
        O[t] = __builtin_amdgcn_mfma_f32_16x16x32_bf16(vf, pfr, O[t], 0, 0, 0);
      }
    }
    __syncthreads();
    cur ^= 1;
  }

  const float inv = 1.0f / l_s;
  const size_t row = (size_t)(b * T_SEQ + qt * 64 + w * 16 + l15);
#pragma unroll
  for (int t = 0; t < 4; t++)
#pragma unroll
    for (int pr = 0; pr < 2; pr++) {
      u16 a0 = f2bf(O[t][pr * 2 + 0] * inv);
      u16 a1 = f2bf(O[t][pr * 2 + 1] * inv);
      *(u32*)&attn[row * D_MODEL + h * HDIM + t * 16 + g * 4 + pr * 2] =
          (u32)a0 | ((u32)a1 << 16);
    }
}

extern "C" void kernel_launch(void* const* d_in, const int* in_sizes, int n_in,
                              void* d_out, int out_size, void* d_ws, size_t ws_size,
                              hipStream_t stream) {
  const float* x = (const float*)d_in[0];
  const float* w_qkv = (const float*)d_in[1];
  const float* w_proj = (const float*)d_in[2];
  float* out = (float*)d_out;
  char* ws = (char*)d_ws;
  const size_t MB = (size_t)1 << 20;
  if (ws_size < 56 * MB) return;  // need 56 MB scratch
  u16* xb = (u16*)(ws + 0);            // 8 MB  [4096][1024] bf16
  u16* wqkvT = (u16*)(ws + 8 * MB);    // 6 MB  [3072][1024] bf16
  u16* wprojT = (u16*)(ws + 14 * MB);  // 2 MB  [1024][1024] bf16
  u16* qkv = (u16*)(ws + 16 * MB);     // 24 MB [4096][3072] bf16
  u16* vT = (u16*)(ws + 40 * MB);      // 8 MB  [32*64][2048] bf16
  u16* attn = (u16*)(ws + 48 * MB);    // 8 MB  [4096][1024] bf16

  convert_bf16_kernel<<<4096, 256, 0, stream>>>(x, xb, (B_SZ * T_SEQ * D_MODEL) / 4);
  transpose_convert<<<dim3(96, 32), dim3(32, 8), 0, stream>>>(w_qkv, wqkvT, D_MODEL, QKV_P);
  transpose_convert<<<dim3(32, 32), dim3(32, 8), 0, stream>>>(w_proj, wprojT, D_MODEL, D_MODEL);
  gemm_bt<0><<<dim3(QKV_P / 128, (B_SZ * T_SEQ) / 128), 256, 0, stream>>>(
      xb, wqkvT, qkv, B_SZ * T_SEQ, QKV_P, D_MODEL);
  transpose_v<<<dim3(T_SEQ / 32, B_SZ * NHEADS * 2), dim3(32, 8), 0, stream>>>(qkv, vT);
  flash_attn<<<dim3(T_SEQ / 64, B_SZ * NHEADS), 256, 0, stream>>>(qkv, vT, attn);
  gemm_bt<1><<<dim3(D_MODEL / 128, (B_SZ * T_SEQ) / 128), 256, 0, stream>>>(
      attn, wprojT, out, B_SZ * T_SEQ, D_MODEL, D_MODEL);
}

// Round 5
// 179.519 us; speedup vs baseline: 1.1701x; 1.0628x over previous
//
#include <hip/hip_runtime.h>
#include <stdint.h>

#define B_SZ 2
#define T_SEQ 2048
#define D_MODEL 1024
#define NHEADS 16
#define HDIM 64
#define QKV_P (3 * D_MODEL) /* 3072 */

typedef unsigned short u16;
typedef uint32_t u32;
typedef __attribute__((ext_vector_type(4))) float f32x4;
typedef __attribute__((ext_vector_type(8))) short s16x8;

__device__ __forceinline__ u16 f2bf(float f) {
  union { float f; uint32_t u; } v; v.f = f;
  uint32_t r = v.u + 0x7fffu + ((v.u >> 16) & 1u);
  return (u16)(r >> 16);
}

__device__ __forceinline__ void async16(const void* g, void* l) {
  __builtin_amdgcn_global_load_lds((const __attribute__((address_space(1))) void*)g,
                                   (__attribute__((address_space(3))) void*)l,
                                   16, 0, 0);
}

// ---------------- fp32 -> bf16 convert (x) ----------------
__global__ void convert_bf16_kernel(const float* __restrict__ in, u16* __restrict__ out, int n4) {
  int i = blockIdx.x * blockDim.x + threadIdx.x;
  if (i < n4) {
    float4 v = ((const float4*)in)[i];
    ushort4 o;
    o.x = f2bf(v.x); o.y = f2bf(v.y); o.z = f2bf(v.z); o.w = f2bf(v.w);
    ((ushort4*)out)[i] = o;
  }
}

// ---------------- fp32 [R][C] -> bf16 [C][R] (weights) ----------------
__global__ void transpose_convert(const float* __restrict__ in, u16* __restrict__ out, int R, int C) {
  __shared__ float tile[32][33];
  const int tx = threadIdx.x, ty = threadIdx.y;
  const int c0 = blockIdx.x * 32, r0 = blockIdx.y * 32;
#pragma unroll
  for (int i = 0; i < 4; i++)
    tile[ty + i * 8][tx] = in[(size_t)(r0 + ty + i * 8) * C + c0 + tx];
  __syncthreads();
#pragma unroll
  for (int i = 0; i < 4; i++)
    out[(size_t)(c0 + ty + i * 8) * R + r0 + tx] = f2bf(tile[tx][ty + i * 8]);
}

// ---------------- V section of qkv -> VT[bh*64+hd][T] ----------------
__global__ void transpose_v(const u16* __restrict__ qkv, u16* __restrict__ vT) {
  __shared__ u16 tile[32][33];
  const int tx = threadIdx.x, ty = threadIdx.y;
  const int tt = blockIdx.x * 32;
  const int bh = blockIdx.y >> 1, hdt = blockIdx.y & 1;
  const int b = bh >> 4, h = bh & 15;
  const int hh = hdt * 32;
#pragma unroll
  for (int i = 0; i < 4; i++)
    tile[ty + i * 8][tx] =
        qkv[(size_t)(b * T_SEQ + tt + ty + i * 8) * QKV_P + 2 * D_MODEL + h * HDIM + hh + tx];
  __syncthreads();
#pragma unroll
  for (int i = 0; i < 4; i++)
    vT[(size_t)(bh * HDIM + hh + ty + i * 8) * T_SEQ + tt + tx] = tile[tx][ty + i * 8];
}

// ---------------- m97-style bf16 GEMM: C[M,N] = A[M,K] * BT[N,K]^T ----------------
template <int F32OUT>
__global__ __launch_bounds__(256) void gemm_bt(const u16* __restrict__ A,
                                               const u16* __restrict__ BT,
                                               void* __restrict__ Cout,
                                               int M, int N, int K) {
  __shared__ u16 As[128 * 32];
  __shared__ u16 Bs[128 * 32];
  const int tid = threadIdx.x;
  const int lane = tid & 63, w = tid >> 6;
  const int l15 = lane & 15, g = lane >> 4;
  const int wr = w >> 1, wc = w & 1;
  const int bn = blockIdx.x, bm = blockIdx.y;
  const u16* Ab = A + (size_t)bm * 128 * K;
  const u16* Bb = BT + (size_t)bn * 128 * K;
  f32x4 acc[4][4];
#pragma unroll
  for (int i = 0; i < 4; i++)
#pragma unroll
    for (int j = 0; j < 4; j++) acc[i][j] = (f32x4){0.f, 0.f, 0.f, 0.f};
  const int c0 = tid, c1 = tid + 256;
  for (int kt = 0; kt < K; kt += 32) {
    async16(Ab + (size_t)(c0 >> 2) * K + kt + (c0 & 3) * 8, (char*)As + c0 * 16);
    async16(Ab + (size_t)(c1 >> 2) * K + kt + (c1 & 3) * 8, (char*)As + c1 * 16);
    async16(Bb + (size_t)(c0 >> 2) * K + kt + (c0 & 3) * 8, (char*)Bs + c0 * 16);
    async16(Bb + (size_t)(c1 >> 2) * K + kt + (c1 & 3) * 8, (char*)Bs + c1 * 16);
    asm volatile("s_waitcnt vmcnt(0)" ::: "memory");
    __syncthreads();
    s16x8 af[4], bfr[4];
#pragma unroll
    for (int i = 0; i < 4; i++)
      af[i] = *(const s16x8*)(As + (wr * 64 + i * 16 + l15) * 32 + g * 8);
#pragma unroll
    for (int j = 0; j < 4; j++)
      bfr[j] = *(const s16x8*)(Bs + (wc * 64 + j * 16 + l15) * 32 + g * 8);
#pragma unroll
    for (int i = 0; i < 4; i++)
#pragma unroll
      for (int j = 0; j < 4; j++)
        acc[i][j] = __builtin_amdgcn_mfma_f32_16x16x32_bf16(af[i], bfr[j], acc[i][j], 0, 0, 0);
    __syncthreads();
  }
#pragma unroll
  for (int i = 0; i < 4; i++) {
    const int row0 = bm * 128 + wr * 64 + i * 16 + g * 4;
#pragma unroll
    for (int j = 0; j < 4; j++) {
      const int col = bn * 128 + wc * 64 + j * 16 + l15;
#pragma unroll
      for (int r = 0; r < 4; r++) {
        if (F32OUT)
          ((float*)Cout)[(size_t)(row0 + r) * N + col] = acc[i][j][r];
        else
          ((u16*)Cout)[(size_t)(row0 + r) * N + col] = f2bf(acc[i][j][r]);
      }
    }
  }
}

// ---------------- causal flash attention: independent single-wave blocks ----------------
// 2048 blocks x 64 threads. Block id -> (bh, strip): xcd-pinned (id&7 -> 4 heads per XCD),
// heavy strips first. Each wave owns 32 q-rows (2 x 16-col groups), K/V direct from global
// into MFMA fragments (no LDS staging, no barriers). Ps = wave-private reshape buffer.
#define PP 88 /* Ps pitch in elements; 176B rows, b128-aligned */
__global__ __launch_bounds__(64, 3) void flash_attn(const u16* __restrict__ qkv,
                                                    const u16* __restrict__ vT,
                                                    u16* __restrict__ attn) {
  __shared__ u16 Ps[32 * PP];
  const int tid = threadIdx.x;
  const int l15 = tid & 15, g = tid >> 4;
  const int id = blockIdx.x;
  const int bh = ((id & 7) << 2) | ((id >> 3) & 3);  // XCD-pinned: id%8 -> head group
  const int s = 63 - (id >> 5);                      // 32-row strip, heavy-first
  const int b = bh >> 4, h = bh & 15;

  // Q fragments: qf[qc][kk], B-layout col = l15 (query qc*16+l15), k = kk*32+g*8+j
  s16x8 qf[2][2];
#pragma unroll
  for (int qc = 0; qc < 2; qc++)
#pragma unroll
    for (int kk = 0; kk < 2; kk++)
      qf[qc][kk] = *(const s16x8*)(qkv + (size_t)(b * T_SEQ + s * 32 + qc * 16 + l15) * QKV_P +
                                   h * HDIM + kk * 32 + g * 8);

  f32x4 O[2][4];  // O^T: lane holds O[hd=t*16+g*4+r][query=qc*16+l15]
#pragma unroll
  for (int qc = 0; qc < 2; qc++)
#pragma unroll
    for (int t = 0; t < 4; t++) O[qc][t] = (f32x4){0.f, 0.f, 0.f, 0.f};
  float m_s[2] = {-1e30f, -1e30f}, l_s[2] = {0.f, 0.f};
  const float sc = 0.18033688011112042f;  // (1/sqrt(64)) * log2(e)

  const int nt = (s >> 1) + 1;
  const u16* kbase = qkv + (size_t)b * T_SEQ * QKV_P + D_MODEL + h * HDIM;
  const u16* vbase = vT + (size_t)bh * HDIM * T_SEQ;

  for (int kvt = 0; kvt < nt; ++kvt) {
    // K fragments: A-layout row = key = t16*16+l15, k = kk*32+g*8+j
    s16x8 kf[4][2], vf[4][2];
#pragma unroll
    for (int t16 = 0; t16 < 4; t16++)
#pragma unroll
      for (int kk = 0; kk < 2; kk++)
        kf[t16][kk] = *(const s16x8*)(kbase + (size_t)(kvt * 64 + t16 * 16 + l15) * QKV_P +
                                      kk * 32 + g * 8);
    // V^T fragments: A-layout row = hd = t*16+l15, k = key = kk*32+g*8+j
#pragma unroll
    for (int t = 0; t < 4; t++)
#pragma unroll
      for (int kk = 0; kk < 2; kk++)
        vf[t][kk] = *(const s16x8*)(vbase + (size_t)(t * 16 + l15) * T_SEQ + kvt * 64 +
                                    kk * 32 + g * 8);

    // S^T[key][query] = K Q^T
    f32x4 S[2][4];
#pragma unroll
    for (int qc = 0; qc < 2; qc++)
#pragma unroll
      for (int t16 = 0; t16 < 4; t16++) S[qc][t16] = (f32x4){0.f, 0.f, 0.f, 0.f};
#pragma unroll
    for (int qc = 0; qc < 2; qc++)
#pragma unroll
      for (int t16 = 0; t16 < 4; t16++)
#pragma unroll
        for (int kk = 0; kk < 2; kk++)
          S[qc][t16] =
              __builtin_amdgcn_mfma_f32_16x16x32_bf16(kf[t16][kk], qf[qc][kk], S[qc][t16], 0, 0, 0);

    const bool diag = (kvt == nt - 1);
#pragma unroll
    for (int qc = 0; qc < 2; qc++) {
      const int qrl = (s & 1) * 32 + qc * 16 + l15;  // query pos within this kv tile's frame
      float x[16];
#pragma unroll
      for (int t16 = 0; t16 < 4; t16++)
#pragma unroll
        for (int r = 0; r < 4; r++) {
          float v = S[qc][t16][r] * sc;
          if (diag && (t16 * 16 + g * 4 + r) > qrl) v = -3e38f;
          x[t16 * 4 + r] = v;
        }
      float mx = x[0];
#pragma unroll
      for (int i = 1; i < 16; i++) mx = fmaxf(mx, x[i]);
      mx = fmaxf(mx, __shfl_xor(mx, 16));
      mx = fmaxf(mx, __shfl_xor(mx, 32));
      const float mnew = fmaxf(m_s[qc], mx);
      const float alpha = exp2f(m_s[qc] - mnew);
      m_s[qc] = mnew;
      float ps = 0.f;
      u16 pb[16];
#pragma unroll
      for (int i = 0; i < 16; i++) {
        float p = exp2f(x[i] - mnew);
        ps += p;
        pb[i] = f2bf(p);
      }
      ps += __shfl_xor(ps, 16);
      ps += __shfl_xor(ps, 32);
      l_s[qc] = l_s[qc] * alpha + ps;
#pragma unroll
      for (int t = 0; t < 4; t++)
#pragma unroll
        for (int r = 0; r < 4; r++) O[qc][t][r] *= alpha;
      // write P[query=qc*16+l15][key=t16*16+g*4+{0..3}] as u32 pairs
#pragma unroll
      for (int t16 = 0; t16 < 4; t16++)
#pragma unroll
        for (int pr = 0; pr < 2; pr++) {
          u32 w32 = (u32)pb[t16 * 4 + pr * 2] | ((u32)pb[t16 * 4 + pr * 2 + 1] << 16);
          *(u32*)((char*)Ps + ((qc * 16 + l15) * PP + t16 * 16 + g * 4 + pr * 2) * 2) = w32;
        }
    }
    asm volatile("s_waitcnt lgkmcnt(0)" ::: "memory");

    // O^T += V^T P^T : mfma(A = vf, B = P-frag[col=query, k=key])
#pragma unroll
    for (int qc = 0; qc < 2; qc++)
#pragma unroll
      for (int kk = 0; kk < 2; kk++) {
        s16x8 pfr =
            *(const s16x8*)((const char*)Ps + (qc * 16 + l15) * (PP * 2) + kk * 64 + g * 16);
#pragma unroll
        for (int t = 0; t < 4; t++)
          O[qc][t] = __builtin_amdgcn_mfma_f32_16x16x32_bf16(vf[t][kk], pfr, O[qc][t], 0, 0, 0);
      }
  }

#pragma unroll
  for (int qc = 0; qc < 2; qc++) {
    const float inv = 1.0f / l_s[qc];
    const size_t row = (size_t)(b * T_SEQ + s * 32 + qc * 16 + l15);
#pragma unroll
    for (int t = 0; t < 4; t++)
#pragma unroll
      for (int pr = 0; pr < 2; pr++) {
        u16 a0 = f2bf(O[qc][t][pr * 2 + 0] * inv);
        u16 a1 = f2bf(O[qc][t][pr * 2 + 1] * inv);
        *(u32*)&attn[row * D_MODEL + h * HDIM + t * 16 + g * 4 + pr * 2] =
            (u32)a0 | ((u32)a1 << 16);
      }
  }
}

extern "C" void kernel_launch(void* const* d_in, const int* in_sizes, int n_in,
                              void* d_out, int out_size, void* d_ws, size_t ws_size,
                              hipStream_t stream) {
  const float* x = (const float*)d_in[0];
  const float* w_qkv = (const float*)d_in[1];
  const float* w_proj = (const float*)d_in[2];
  float* out = (float*)d_out;
  char* ws = (char*)d_ws;
  const size_t MB = (size_t)1 << 20;
  if (ws_size < 56 * MB) return;  // need 56 MB scratch
  u16* xb = (u16*)(ws + 0);            // 8 MB  [4096][1024] bf16
  u16* wqkvT = (u16*)(ws + 8 * MB);    // 6 MB  [3072][1024] bf16
  u16* wprojT = (u16*)(ws + 14 * MB);  // 2 MB  [1024][1024] bf16
  u16* qkv = (u16*)(ws + 16 * MB);     // 24 MB [4096][3072] bf16
  u16* vT = (u16*)(ws + 40 * MB);      // 8 MB  [32*64][2048] bf16
  u16* attn = (u16*)(ws + 48 * MB);    // 8 MB  [4096][1024] bf16

  convert_bf16_kernel<<<4096, 256, 0, stream>>>(x, xb, (B_SZ * T_SEQ * D_MODEL) / 4);
  transpose_convert<<<dim3(96, 32), dim3(32, 8), 0, stream>>>(w_qkv, wqkvT, D_MODEL, QKV_P);
  transpose_convert<<<dim3(32, 32), dim3(32, 8), 0, stream>>>(w_proj, wprojT, D_MODEL, D_MODEL);
  gemm_bt<0><<<dim3(QKV_P / 128, (B_SZ * T_SEQ) / 128), 256, 0, stream>>>(
      xb, wqkvT, qkv, B_SZ * T_SEQ, QKV_P, D_MODEL);
  transpose_v<<<dim3(T_SEQ / 32, B_SZ * NHEADS * 2), dim3(32, 8), 0, stream>>>(qkv, vT);
  flash_attn<<<2048, 64, 0, stream>>>(qkv, vT, attn);
  gemm_bt<1><<<dim3(D_MODEL / 128, (B_SZ * T_SEQ) / 128), 256, 0, stream>>>(
      attn, wprojT, out, B_SZ * T_SEQ, D_MODEL, D_MODEL);
}

// Round 7
// 133.173 us; speedup vs baseline: 1.5773x; 1.3480x over previous
//
#include <hip/hip_runtime.h>
#include <stdint.h>

#define B_SZ 2
#define T_SEQ 2048
#define D_MODEL 1024
#define NHEADS 16
#define HDIM 64
#define QKV_P (3 * D_MODEL) /* 3072 */

typedef unsigned short u16;
typedef uint32_t u32;
typedef __attribute__((ext_vector_type(4))) float f32x4;
typedef __attribute__((ext_vector_type(8))) short s16x8;

__device__ __forceinline__ u16 f2bf(float f) {
  union { float f; uint32_t u; } v; v.f = f;
  uint32_t r = v.u + 0x7fffu + ((v.u >> 16) & 1u);
  return (u16)(r >> 16);
}

__device__ __forceinline__ float fastexp2(float x) {
  float r;
  asm volatile("v_exp_f32 %0, %1" : "=v"(r) : "v"(x));
  return r;
}

__device__ __forceinline__ u32 cvtpk(float lo, float hi) {
  u32 r;
  asm volatile("v_cvt_pk_bf16_f32 %0, %1, %2" : "=v"(r) : "v"(lo), "v"(hi));
  return r;
}

__device__ __forceinline__ void async16(const void* g, void* l) {
  __builtin_amdgcn_global_load_lds((const __attribute__((address_space(1))) void*)g,
                                   (__attribute__((address_space(3))) void*)l,
                                   16, 0, 0);
}

// ---------------- fp32 -> bf16 convert (x) ----------------
__global__ void convert_bf16_kernel(const float* __restrict__ in, u16* __restrict__ out, int n4) {
  int i = blockIdx.x * blockDim.x + threadIdx.x;
  if (i < n4) {
    float4 v = ((const float4*)in)[i];
    ushort4 o;
    o.x = f2bf(v.x); o.y = f2bf(v.y); o.z = f2bf(v.z); o.w = f2bf(v.w);
    ((ushort4*)out)[i] = o;
  }
}

// ---------------- fp32 [R][C] -> bf16 [C][R] (weights) ----------------
__global__ void transpose_convert(const float* __restrict__ in, u16* __restrict__ out, int R, int C) {
  __shared__ float tile[32][33];
  const int tx = threadIdx.x, ty = threadIdx.y;
  const int c0 = blockIdx.x * 32, r0 = blockIdx.y * 32;
#pragma unroll
  for (int i = 0; i < 4; i++)
    tile[ty + i * 8][tx] = in[(size_t)(r0 + ty + i * 8) * C + c0 + tx];
  __syncthreads();
#pragma unroll
  for (int i = 0; i < 4; i++)
    out[(size_t)(c0 + ty + i * 8) * R + r0 + tx] = f2bf(tile[tx][ty + i * 8]);
}

// ---------------- V section of qkv -> VT[bh*64+hd][T] ----------------
__global__ void transpose_v(const u16* __restrict__ qkv, u16* __restrict__ vT) {
  __shared__ u16 tile[32][33];
  const int tx = threadIdx.x, ty = threadIdx.y;
  const int tt = blockIdx.x * 32;
  const int bh = blockIdx.y >> 1, hdt = blockIdx.y & 1;
  const int b = bh >> 4, h = bh & 15;
  const int hh = hdt * 32;
#pragma unroll
  for (int i = 0; i < 4; i++)
    tile[ty + i * 8][tx] =
        qkv[(size_t)(b * T_SEQ + tt + ty + i * 8) * QKV_P + 2 * D_MODEL + h * HDIM + hh + tx];
  __syncthreads();
#pragma unroll
  for (int i = 0; i < 4; i++)
    vT[(size_t)(bh * HDIM + hh + ty + i * 8) * T_SEQ + tt + tx] = tile[tx][ty + i * 8];
}

// ---------------- m97-style bf16 GEMM: C[M,N] = A[M,K] * BT[N,K]^T ----------------
template <int F32OUT>
__global__ __launch_bounds__(256) void gemm_bt(const u16* __restrict__ A,
                                               const u16* __restrict__ BT,
                                               void* __restrict__ Cout,
                                               int M, int N, int K) {
  __shared__ u16 As[128 * 32];
  __shared__ u16 Bs[128 * 32];
  const int tid = threadIdx.x;
  const int lane = tid & 63, w = tid >> 6;
  const int l15 = lane & 15, g = lane >> 4;
  const int wr = w >> 1, wc = w & 1;
  const int bn = blockIdx.x, bm = blockIdx.y;
  const u16* Ab = A + (size_t)bm * 128 * K;
  const u16* Bb = BT + (size_t)bn * 128 * K;
  f32x4 acc[4][4];
#pragma unroll
  for (int i = 0; i < 4; i++)
#pragma unroll
    for (int j = 0; j < 4; j++) acc[i][j] = (f32x4){0.f, 0.f, 0.f, 0.f};
  const int c0 = tid, c1 = tid + 256;
  for (int kt = 0; kt < K; kt += 32) {
    async16(Ab + (size_t)(c0 >> 2) * K + kt + (c0 & 3) * 8, (char*)As + c0 * 16);
    async16(Ab + (size_t)(c1 >> 2) * K + kt + (c1 & 3) * 8, (char*)As + c1 * 16);
    async16(Bb + (size_t)(c0 >> 2) * K + kt + (c0 & 3) * 8, (char*)Bs + c0 * 16);
    async16(Bb + (size_t)(c1 >> 2) * K + kt + (c1 & 3) * 8, (char*)Bs + c1 * 16);
    asm volatile("s_waitcnt vmcnt(0)" ::: "memory");
    __syncthreads();
    s16x8 af[4], bfr[4];
#pragma unroll
    for (int i = 0; i < 4; i++)
      af[i] = *(const s16x8*)(As + (wr * 64 + i * 16 + l15) * 32 + g * 8);
#pragma unroll
    for (int j = 0; j < 4; j++)
      bfr[j] = *(const s16x8*)(Bs + (wc * 64 + j * 16 + l15) * 32 + g * 8);
#pragma unroll
    for (int i = 0; i < 4; i++)
#pragma unroll
      for (int j = 0; j < 4; j++)
        acc[i][j] = __builtin_amdgcn_mfma_f32_16x16x32_bf16(af[i], bfr[j], acc[i][j], 0, 0, 0);
    __syncthreads();
  }
#pragma unroll
  for (int i = 0; i < 4; i++) {
    const int row0 = bm * 128 + wr * 64 + i * 16 + g * 4;
#pragma unroll
    for (int j = 0; j < 4; j++) {
      const int col = bn * 128 + wc * 64 + j * 16 + l15;
#pragma unroll
      for (int r = 0; r < 4; r++) {
        if (F32OUT)
          ((float*)Cout)[(size_t)(row0 + r) * N + col] = acc[i][j][r];
        else
          ((u16*)Cout)[(size_t)(row0 + r) * N + col] = f2bf(acc[i][j][r]);
      }
    }
  }
}

// ---------------- causal flash attention v7 ----------------
// Same as v6 but with the P-redistribution corrected: shuffle BOTH candidate
// registers, select AFTER the shuffle with the destination's hi = g>>1.
__global__ __launch_bounds__(256, 3) void flash_attn(const u16* __restrict__ qkv,
                                                     const u16* __restrict__ vT,
                                                     u16* __restrict__ attn) {
  __shared__ u16 Ks[2][64 * 64];  // [key][hd], XOR-swizzled
  __shared__ u16 Vs[2][64 * 64];  // [hd][key], XOR-swizzled
  const int tid = threadIdx.x;
  const int lane = tid & 63, w = tid >> 6;
  const int l15 = lane & 15, g = lane >> 4;
  const int id = blockIdx.x;
  const int bh = ((id & 7) << 2) | ((id >> 3) & 3);  // 4 heads per XCD
  const int qs = 31 - (id >> 5);                     // 64-row strip, heavy-first
  const int b = bh >> 4, h = bh & 15;

  // Q fragments (B-layout: col = l15 = q-row, k = kk*32+g*8+j)
  const size_t qrow = (size_t)(b * T_SEQ + qs * 64 + w * 16 + l15);
  s16x8 qf[2];
  qf[0] = *(const s16x8*)(qkv + qrow * QKV_P + h * HDIM + 0 * 32 + g * 8);
  qf[1] = *(const s16x8*)(qkv + qrow * QKV_P + h * HDIM + 1 * 32 + g * 8);

  f32x4 O[4];  // O^T: lane holds O[hd = t*16+g*4+r][query = l15]
#pragma unroll
  for (int t = 0; t < 4; t++) O[t] = (f32x4){0.f, 0.f, 0.f, 0.f};
  float m_s = -1e30f, l_s = 0.f;          // raw-score units
  const int qrl = w * 16 + l15;           // q-row within strip
  const float sc = 0.18033688011112042f;  // (1/sqrt(64)) * log2(e)
  const int lA = l15 + ((g & 1) << 5), hi = g >> 1;

#define STAGE(buf, kvt_)                                                                     \
  do {                                                                                       \
    _Pragma("unroll") for (int i_ = 0; i_ < 2; i_++) {                                       \
      int o_ = (tid + i_ * 256) * 16;                                                        \
      int lo_ = o_ ^ (((o_ >> 7) & 7) << 4);                                                 \
      int row_ = lo_ >> 7;                                                                   \
      int byt_ = lo_ & 127;                                                                  \
      async16(qkv + (size_t)(b * T_SEQ + (kvt_) * 64 + row_) * QKV_P + D_MODEL + h * HDIM +  \
                  (byt_ >> 1),                                                               \
              (char*)Ks[buf] + o_);                                                          \
      async16(vT + (size_t)(bh * HDIM + row_) * T_SEQ + (kvt_) * 64 + (byt_ >> 1),           \
              (char*)Vs[buf] + o_);                                                          \
    }                                                                                        \
  } while (0)

  STAGE(0, 0);
  int cur = 0;
  const int nt = qs + 1;
  for (int kvt = 0; kvt < nt; ++kvt) {
    if (kvt < qs) {
      STAGE(cur ^ 1, kvt + 1);
      asm volatile("s_waitcnt vmcnt(4)" ::: "memory");
    } else {
      asm volatile("s_waitcnt vmcnt(0)" ::: "memory");
    }
    __syncthreads();

    // S^T = K Q^T: lane (l15,g) holds S[query=l15][key = t16*16+g*4+r]
    f32x4 S[4];
#pragma unroll
    for (int t16 = 0; t16 < 4; t16++) S[t16] = (f32x4){0.f, 0.f, 0.f, 0.f};
#pragma unroll
    for (int t16 = 0; t16 < 4; t16++)
#pragma unroll
      for (int kk = 0; kk < 2; kk++) {
        int key = t16 * 16 + l15;
        int bp = (key * 128 + kk * 64 + g * 16) ^ ((key & 7) << 4);
        s16x8 kf = *(const s16x8*)((const char*)Ks[cur] + bp);
        S[t16] = __builtin_amdgcn_mfma_f32_16x16x32_bf16(kf, qf[kk], S[t16], 0, 0, 0);
      }

    if (kvt == qs) {  // diagonal tile: causal mask (raw units)
#pragma unroll
      for (int t16 = 0; t16 < 4; t16++)
#pragma unroll
        for (int r = 0; r < 4; r++)
          if (t16 * 16 + g * 4 + r > qrl) S[t16][r] = -3e38f;
    }
    float mx = fmaxf(fmaxf(fmaxf(S[0][0], S[0][1]), fmaxf(S[0][2], S[0][3])),
                     fmaxf(fmaxf(S[1][0], S[1][1]), fmaxf(S[1][2], S[1][3])));
    mx = fmaxf(mx, fmaxf(fmaxf(fmaxf(S[2][0], S[2][1]), fmaxf(S[2][2], S[2][3])),
                         fmaxf(fmaxf(S[3][0], S[3][1]), fmaxf(S[3][2], S[3][3]))));
    mx = fmaxf(mx, __shfl_xor(mx, 16));
    mx = fmaxf(mx, __shfl_xor(mx, 32));
    const float mnew = fmaxf(m_s, mx);
    const float alpha = fastexp2((m_s - mnew) * sc);
    m_s = mnew;
    const float msc = mnew * sc;
    float p[16];
#pragma unroll
    for (int t16 = 0; t16 < 4; t16++)
#pragma unroll
      for (int r = 0; r < 4; r++) p[t16 * 4 + r] = fastexp2(fmaf(S[t16][r], sc, -msc));
    float ps = 0.f;
#pragma unroll
    for (int i = 0; i < 16; i++) ps += p[i];
    ps += __shfl_xor(ps, 16);
    ps += __shfl_xor(ps, 32);
    l_s = l_s * alpha + ps;
#pragma unroll
    for (int t = 0; t < 4; t++)
#pragma unroll
      for (int r = 0; r < 4; r++) O[t][r] *= alpha;

    // pack P to bf16 pairs: c[t16][q] = keys t16*16 + g*4 + {2q, 2q+1} for query l15
    u32 c[4][2];
#pragma unroll
    for (int t16 = 0; t16 < 4; t16++) {
      c[t16][0] = cvtpk(p[t16 * 4 + 0], p[t16 * 4 + 1]);
      c[t16][1] = cvtpk(p[t16 * 4 + 2], p[t16 * 4 + 3]);
    }

    // O^T += V^T P^T; PV B-frag: dest lane (l15,g) needs keys kk*32+g*8+{0..7} of
    // query l15 = register c[2kk+(g>>1)][0..1] from lanes (l15, 2(g&1)) and (l15, 2(g&1)+1).
    // Shuffle both candidate registers, select after with the DEST's hi = g>>1.
#pragma unroll
    for (int kk = 0; kk < 2; kk++) {
      u32 s00 = (u32)__shfl((int)c[2 * kk][0], lA);
      u32 s01 = (u32)__shfl((int)c[2 * kk][1], lA);
      u32 s10 = (u32)__shfl((int)c[2 * kk + 1][0], lA);
      u32 s11 = (u32)__shfl((int)c[2 * kk + 1][1], lA);
      u32 t00 = (u32)__shfl((int)c[2 * kk][0], lA + 16);
      u32 t01 = (u32)__shfl((int)c[2 * kk][1], lA + 16);
      u32 t10 = (u32)__shfl((int)c[2 * kk + 1][0], lA + 16);
      u32 t11 = (u32)__shfl((int)c[2 * kk + 1][1], lA + 16);
      union { u32 u[4]; s16x8 v; } pu;
      pu.u[0] = hi ? s10 : s00;
      pu.u[1] = hi ? s11 : s01;
      pu.u[2] = hi ? t10 : t00;
      pu.u[3] = hi ? t11 : t01;
#pragma unroll
      for (int t = 0; t < 4; t++) {
        int hd = t * 16 + l15;
        int bp = (hd * 128 + kk * 64 + g * 16) ^ ((hd & 7) << 4);
        s16x8 vf = *(const s16x8*)((const char*)Vs[cur] + bp);
        O[t] = __builtin_amdgcn_mfma_f32_16x16x32_bf16(vf, pu.v, O[t], 0, 0, 0);
      }
    }
    __syncthreads();
    cur ^= 1;
  }

  const float inv = 1.0f / l_s;
  const size_t row = (size_t)(b * T_SEQ + qs * 64 + w * 16 + l15);
#pragma unroll
  for (int t = 0; t < 4; t++)
#pragma unroll
    for (int pr = 0; pr < 2; pr++) {
      u32 pk = cvtpk(O[t][pr * 2 + 0] * inv, O[t][pr * 2 + 1] * inv);
      *(u32*)&attn[row * D_MODEL + h * HDIM + t * 16 + g * 4 + pr * 2] = pk;
    }
}

extern "C" void kernel_launch(void* const* d_in, const int* in_sizes, int n_in,
                              void* d_out, int out_size, void* d_ws, size_t ws_size,
                              hipStream_t stream) {
  const float* x = (const float*)d_in[0];
  const float* w_qkv = (const float*)d_in[1];
  const float* w_proj = (const float*)d_in[2];
  float* out = (float*)d_out;
  char* ws = (char*)d_ws;
  const size_t MB = (size_t)1 << 20;
  if (ws_size < 56 * MB) return;  // need 56 MB scratch
  u16* xb = (u16*)(ws + 0);            // 8 MB  [4096][1024] bf16
  u16* wqkvT = (u16*)(ws + 8 * MB);    // 6 MB  [3072][1024] bf16
  u16* wprojT = (u16*)(ws + 14 * MB);  // 2 MB  [1024][1024] bf16
  u16* qkv = (u16*)(ws + 16 * MB);     // 24 MB [4096][3072] bf16
  u16* vT = (u16*)(ws + 40 * MB);      // 8 MB  [32*64][2048] bf16
  u16* attn = (u16*)(ws + 48 * MB);    // 8 MB  [4096][1024] bf16

  convert_bf16_kernel<<<4096, 256, 0, stream>>>(x, xb, (B_SZ * T_SEQ * D_MODEL) / 4);
  transpose_convert<<<dim3(96, 32), dim3(32, 8), 0, stream>>>(w_qkv, wqkvT, D_MODEL, QKV_P);
  transpose_convert<<<dim3(32, 32), dim3(32, 8), 0, stream>>>(w_proj, wprojT, D_MODEL, D_MODEL);
  gemm_bt<0><<<dim3(QKV_P / 128, (B_SZ * T_SEQ) / 128), 256, 0, stream>>>(
      xb, wqkvT, qkv, B_SZ * T_SEQ, QKV_P, D_MODEL);
  transpose_v<<<dim3(T_SEQ / 32, B_SZ * NHEADS * 2), dim3(32, 8), 0, stream>>>(qkv, vT);
  flash_attn<<<1024, 256, 0, stream>>>(qkv, vT, attn);
  gemm_bt<1><<<dim3(D_MODEL / 128, (B_SZ * T_SEQ) / 128), 256, 0, stream>>>(
      attn, wprojT, out, B_SZ * T_SEQ, D_MODEL, D_MODEL);
}